// Round 14
// baseline (416.370 us; speedup 1.0000x reference)
//
#include <hip/hip_runtime.h>
#include <hip/hip_cooperative_groups.h>
#include <math.h>

namespace cg = cooperative_groups;

// Problem constants (from reference setup_inputs)
#define BB 512
#define HH 512
#define RR 2048
#define CC 64
#define OUTD 202          // 3*64 + 2*3 + 4
// params workspace layout per batch (floats)
#define PSTRIDE 208
#define K_OFF 0
#define E_OFF 64
#define A_OFF 128
#define S_OFF 192         // 7 softmaxed shift weights
#define COMBO_OFF 199     // beta / k_n
#define G_OFF 200
#define GAMMA_OFF 201

#define PART_STRIDE 224   // padded 202, per (batch, hq) partial row

typedef float f32x4 __attribute__((ext_vector_type(4)));

__device__ __forceinline__ float softplusf_(float x) {
    return (x > 20.f) ? x : log1pf(expf(x));
}
__device__ __forceinline__ float sigmoidf_(float x) {
    return 1.f / (1.f + expf(-x));
}

// ---------------------------------------------------------------------------
// Kernel A1: split-K partial GEMM (proven R11). 256 blocks = 64 bg x 4 hq.
// ---------------------------------------------------------------------------
__global__ __launch_bounds__(256) void params_part_kernel(
    const float* __restrict__ h, const float* __restrict__ fc_w,
    float* __restrict__ part)
{
    __shared__ float h_sh[8][128];
    const int tid = threadIdx.x;
    const int bg = blockIdx.x >> 2;
    const int hq = blockIdx.x & 3;
    const int b0 = bg * 8;
    const int h0 = hq * 128;

    for (int idx = tid; idx < 8 * 128; idx += 256) {
        int j = idx >> 7, i = idx & 127;
        h_sh[j][i] = h[(size_t)(b0 + j) * HH + h0 + i];
    }
    __syncthreads();

    if (tid < OUTD) {
        float acc[8];
        #pragma unroll
        for (int j = 0; j < 8; ++j) acc[j] = 0.f;
        const float4* wr = (const float4*)(fc_w + (size_t)tid * HH + h0);
        #pragma unroll 4
        for (int i4 = 0; i4 < 32; ++i4) {
            float4 wv = wr[i4];
            int i = i4 * 4;
            #pragma unroll
            for (int j = 0; j < 8; ++j) {
                acc[j] = fmaf(wv.x, h_sh[j][i + 0], acc[j]);
                acc[j] = fmaf(wv.y, h_sh[j][i + 1], acc[j]);
                acc[j] = fmaf(wv.z, h_sh[j][i + 2], acc[j]);
                acc[j] = fmaf(wv.w, h_sh[j][i + 3], acc[j]);
            }
        }
        #pragma unroll
        for (int j = 0; j < 8; ++j) {
            part[((size_t)(b0 + j) * 4 + hq) * PART_STRIDE + tid] = acc[j];
        }
    }
}

// ---------------------------------------------------------------------------
// Kernel A2: combine partials + bias -> activations -> packed params (R11).
// ---------------------------------------------------------------------------
__global__ __launch_bounds__(256) void params_combine_kernel(
    const float* __restrict__ part, const float* __restrict__ fc_b,
    float* __restrict__ pw)
{
    __shared__ float z_sh[80];
    const int b = blockIdx.x;
    const int tid = threadIdx.x;
    float* p = pw + (size_t)b * PSTRIDE;

    if (tid < OUTD) {
        const float* q = part + (size_t)b * 4 * PART_STRIDE + tid;
        float z = q[0] + q[PART_STRIDE] + q[2 * PART_STRIDE]
                + q[3 * PART_STRIDE] + fc_b[tid];
        if (tid < 74) z_sh[tid] = z;
        if (tid < 64)                      p[K_OFF + tid] = tanhf(z);
        else if (tid == 65)                p[G_OFF] = sigmoidf_(z);
        else if (tid == 73)                p[GAMMA_OFF] = softplusf_(z) + 1.f;
        else if (tid >= 74 && tid < 138)   p[E_OFF + (tid - 74)] = sigmoidf_(z);
        else if (tid >= 138)               p[A_OFF + (tid - 138)] = tanhf(z);
    }
    __syncthreads();

    if (tid < 64) {
        float kv = tanhf(z_sh[tid]);
        float ss = kv * kv;
        #pragma unroll
        for (int m = 1; m < 64; m <<= 1) ss += __shfl_xor(ss, m, 64);
        if (tid == 0) {
            float kn = fmaxf(sqrtf(ss), 1e-8f);
            float beta = softplusf_(z_sh[64]);
            p[COMBO_OFF] = beta / kn;
            float mx = -1e30f;
            #pragma unroll
            for (int q = 0; q < 7; ++q) mx = fmaxf(mx, z_sh[66 + q]);
            float ev[7], se = 0.f;
            #pragma unroll
            for (int q = 0; q < 7; ++q) {
                ev[q] = __expf(z_sh[66 + q] - mx);
                se += ev[q];
            }
            float inv = 1.f / se;
            #pragma unroll
            for (int q = 0; q < 7; ++q) p[S_OFF + q] = ev[q] * inv;
        }
    }
}

// ---------------------------------------------------------------------------
// 256-thread block reduce, fixed order -> deterministic
// ---------------------------------------------------------------------------
__device__ __forceinline__ float block_reduce_sum4(float v, float* red) {
    #pragma unroll
    for (int m = 1; m < 64; m <<= 1) v += __shfl_xor(v, m, 64);
    int wid = threadIdx.x >> 6;
    if ((threadIdx.x & 63) == 0) red[wid] = v;
    __syncthreads();
    float x = red[0] + red[1] + red[2] + red[3];
    __syncthreads();
    return x;
}

// ---------------------------------------------------------------------------
// COOPERATIVE main kernel: 1024 blocks x 256 threads (4 blocks/CU, all
// co-resident). Block bid owns batch b=bid>>1, rows rbase..rbase+1024.
// phase 1: score its slice (stream memory once, exp fused, esum partial)
// phase 2: fully-parallel weight via halo trick (gate +-3, conv, pow, psum)
// phase 3: normalize + update — re-reads the SAME slice this block streamed
//          in phase 1 (self-locality; only ~10 MB churned in between).
// Two grid.sync()s replace two kernel-boundary drains; no serial weight.
// ---------------------------------------------------------------------------
__global__ __launch_bounds__(256, 4) void coop_kernel(
    const float* __restrict__ memory, const float* __restrict__ prev_w,
    const float* __restrict__ pw, float* __restrict__ sc,
    float* __restrict__ esum, float* __restrict__ wp,
    float* __restrict__ psum, float* __restrict__ out_w,
    float* __restrict__ out_mem)
{
    cg::grid_group grid = cg::this_grid();
    __shared__ float wgs[1030];
    __shared__ float red[4];

    const int tid = threadIdx.x;
    const int bid = blockIdx.x;
    const int b = bid >> 1;
    const int rbase = (bid & 1) * 1024;
    const float* p = pw + (size_t)b * PSTRIDE;
    const float* memb = memory + (size_t)b * RR * CC;

    // ---- phase 1: score ----
    {
        const int lane16 = tid & 15;
        const int rgrp = tid >> 4;            // 0..15
        const float4 k4 = *(const float4*)(p + K_OFF + lane16 * 4);
        const float combo = p[COMBO_OFF];
        float lsum = 0.f;
        #pragma unroll 8
        for (int i = 0; i < 64; ++i) {
            int r = rbase + i * 16 + rgrp;
            float4 m4 = *(const float4*)(memb + (size_t)r * CC + lane16 * 4);
            float num = m4.x * k4.x + m4.y * k4.y + m4.z * k4.z + m4.w * k4.w;
            float ssq = m4.x * m4.x + m4.y * m4.y + m4.z * m4.z + m4.w * m4.w;
            #pragma unroll
            for (int m = 1; m < 16; m <<= 1) {
                num += __shfl_xor(num, m, 64);
                ssq += __shfl_xor(ssq, m, 64);
            }
            if (lane16 == 0) {
                float mn = fmaxf(sqrtf(ssq), 1e-8f);
                float ev = __expf(combo * num / mn);
                sc[(size_t)b * RR + r] = ev;
                lsum += ev;
            }
        }
        float bs = block_reduce_sum4(lsum, red);
        if (tid == 0) esum[bid] = bs;
    }
    grid.sync();

    // ---- phase 2: gate (+-3 halo) -> conv -> pow -> psum partial ----
    const float g = p[G_OFF];
    const float gamma = p[GAMMA_OFF];
    {
        const float s0 = p[S_OFF + 0], s1 = p[S_OFF + 1], s2 = p[S_OFF + 2],
                    s3 = p[S_OFF + 3], s4 = p[S_OFF + 4], s5 = p[S_OFF + 5],
                    s6 = p[S_OFF + 6];
        const float se = esum[2 * b] + esum[2 * b + 1];
        const float gi = g / se, omg = 1.f - g;

        for (int idx = tid; idx < 1030; idx += 256) {
            int r = (rbase - 3 + idx) & (RR - 1);
            wgs[idx] = gi * sc[(size_t)b * RR + r]
                     + omg * prev_w[(size_t)b * RR + r];
        }
        __syncthreads();

        float lp = 0.f;
        #pragma unroll
        for (int t = 0; t < 4; ++t) {
            int idx = t * 256 + tid;
            float acc = s0 * wgs[idx]     + s1 * wgs[idx + 1]
                      + s2 * wgs[idx + 2] + s3 * wgs[idx + 3]
                      + s4 * wgs[idx + 4] + s5 * wgs[idx + 5]
                      + s6 * wgs[idx + 6];
            float v = __powf(acc, gamma);
            wp[(size_t)b * RR + rbase + idx] = v;
            lp += v;
        }
        float bs = block_reduce_sum4(lp, red);
        if (tid == 0) psum[bid] = bs;
    }
    grid.sync();

    // ---- phase 3: normalize + update (slice is L3-hot from phase 1) ----
    {
        const float invp = 1.f / (psum[2 * b] + psum[2 * b + 1] + 1e-16f);
        const float* wpb = wp + (size_t)b * RR;

        // vectorized out_w write: 4 rows/thread
        #pragma unroll
        for (int t = 0; t < 2; ++t) {
            int r2 = rbase + (t * 256 + tid) * 2;
            float2 wv2 = *(const float2*)(wpb + r2);
            *(float2*)(out_w + (size_t)b * RR + r2) =
                make_float2(wv2.x * invp, wv2.y * invp);
        }

        const int lane8 = tid & 7;
        const int rgrp = tid >> 3;            // 0..31
        const f32x4 ea = *(const f32x4*)(p + E_OFF + lane8 * 8);
        const f32x4 eb2 = *(const f32x4*)(p + E_OFF + lane8 * 8 + 4);
        const f32x4 aa = *(const f32x4*)(p + A_OFF + lane8 * 8);
        const f32x4 ab = *(const f32x4*)(p + A_OFF + lane8 * 8 + 4);
        float* omb = out_mem + (size_t)b * RR * CC;

        #pragma unroll
        for (int mi = 0; mi < 8; ++mi) {
            f32x4 ma[4], mb[4];
            float wv[4];
            #pragma unroll
            for (int j = 0; j < 4; ++j) {
                int r = rbase + (mi * 4 + j) * 32 + rgrp;
                const f32x4* mp =
                    (const f32x4*)(memb + (size_t)r * CC + lane8 * 8);
                ma[j] = mp[0];
                mb[j] = mp[1];
                wv[j] = wpb[r] * invp;
            }
            #pragma unroll
            for (int j = 0; j < 4; ++j) {
                int r = rbase + (mi * 4 + j) * 32 + rgrp;
                f32x4 oa, ob;
                oa.x = ma[j].x * (1.f - wv[j] * ea.x) + wv[j] * aa.x;
                oa.y = ma[j].y * (1.f - wv[j] * ea.y) + wv[j] * aa.y;
                oa.z = ma[j].z * (1.f - wv[j] * ea.z) + wv[j] * aa.z;
                oa.w = ma[j].w * (1.f - wv[j] * ea.w) + wv[j] * aa.w;
                ob.x = mb[j].x * (1.f - wv[j] * eb2.x) + wv[j] * ab.x;
                ob.y = mb[j].y * (1.f - wv[j] * eb2.y) + wv[j] * ab.y;
                ob.z = mb[j].z * (1.f - wv[j] * eb2.z) + wv[j] * ab.z;
                ob.w = mb[j].w * (1.f - wv[j] * eb2.w) + wv[j] * ab.w;
                f32x4* op = (f32x4*)(omb + (size_t)r * CC + lane8 * 8);
                op[0] = oa;
                op[1] = ob;
            }
        }
    }
}

// ---------------------------------------------------------------------------
// Fallback path: proven R12 kernels (score / weight / update).
// ---------------------------------------------------------------------------
__global__ __launch_bounds__(256) void score_kernel(
    const float* __restrict__ memory, const float* __restrict__ pw,
    float* __restrict__ sc, float* __restrict__ esum)
{
    __shared__ float red[4];
    const int tid = threadIdx.x;
    const int b = blockIdx.x >> 2;
    const int rbase = (blockIdx.x & 3) * 512;
    const int lane16 = tid & 15;
    const int rgrp = tid >> 4;
    const float* p = pw + (size_t)b * PSTRIDE;
    const float4 k4 = *(const float4*)(p + K_OFF + lane16 * 4);
    const float combo = p[COMBO_OFF];
    const float* memb = memory + (size_t)b * RR * CC;

    float lsum = 0.f;
    #pragma unroll 8
    for (int i = 0; i < 32; ++i) {
        int r = rbase + i * 16 + rgrp;
        float4 m4 = *(const float4*)(memb + (size_t)r * CC + lane16 * 4);
        float num = m4.x * k4.x + m4.y * k4.y + m4.z * k4.z + m4.w * k4.w;
        float ssq = m4.x * m4.x + m4.y * m4.y + m4.z * m4.z + m4.w * m4.w;
        #pragma unroll
        for (int m = 1; m < 16; m <<= 1) {
            num += __shfl_xor(num, m, 64);
            ssq += __shfl_xor(ssq, m, 64);
        }
        if (lane16 == 0) {
            float mn = fmaxf(sqrtf(ssq), 1e-8f);
            float ev = __expf(combo * num / mn);
            sc[(size_t)b * RR + r] = ev;
            lsum += ev;
        }
    }
    float bs = block_reduce_sum4(lsum, red);
    if (tid == 0) esum[blockIdx.x] = bs;
}

__global__ __launch_bounds__(256) void weight_kernel(
    const float* __restrict__ sc, const float* __restrict__ esum,
    const float* __restrict__ prev_w, const float* __restrict__ pw,
    float* __restrict__ out_w)
{
    __shared__ float buf[RR];
    __shared__ float wg[RR];
    __shared__ float red[4];
    const int b = blockIdx.x;
    const int tid = threadIdx.x;
    const float* p = pw + (size_t)b * PSTRIDE;
    const float g = p[G_OFF];
    const float gamma = p[GAMMA_OFF];
    const float s0 = p[S_OFF + 0], s1 = p[S_OFF + 1], s2 = p[S_OFF + 2],
                s3 = p[S_OFF + 3], s4 = p[S_OFF + 4], s5 = p[S_OFF + 5],
                s6 = p[S_OFF + 6];
    const float* eb = esum + (size_t)b * 4;
    const float se = eb[0] + eb[1] + eb[2] + eb[3];
    const float gi = g / se, omg = 1.f - g;

    #pragma unroll
    for (int t = 0; t < 4; ++t) {
        int r2 = (t * 256 + tid) * 2;
        float2 ev = *(const float2*)(sc + (size_t)b * RR + r2);
        float2 pv = *(const float2*)(prev_w + (size_t)b * RR + r2);
        wg[r2]     = gi * ev.x + omg * pv.x;
        wg[r2 + 1] = gi * ev.y + omg * pv.y;
    }
    __syncthreads();

    float lp = 0.f;
    #pragma unroll
    for (int t = 0; t < 8; ++t) {
        int r = t * 256 + tid;
        float acc = s0 * wg[(r - 3) & (RR - 1)]
                  + s1 * wg[(r - 2) & (RR - 1)]
                  + s2 * wg[(r - 1) & (RR - 1)]
                  + s3 * wg[r]
                  + s4 * wg[(r + 1) & (RR - 1)]
                  + s5 * wg[(r + 2) & (RR - 1)]
                  + s6 * wg[(r + 3) & (RR - 1)];
        float v = __powf(acc, gamma);
        buf[r] = v;
        lp += v;
    }
    const float ps = block_reduce_sum4(lp, red);
    const float invp = 1.f / (ps + 1e-16f);

    #pragma unroll
    for (int t = 0; t < 4; ++t) {
        int r2 = (t * 256 + tid) * 2;
        *(float2*)(out_w + (size_t)b * RR + r2) =
            make_float2(buf[r2] * invp, buf[r2 + 1] * invp);
    }
}

__global__ __launch_bounds__(256) void update_kernel(
    const float* __restrict__ memory, const float* __restrict__ w,
    const float* __restrict__ pw, float* __restrict__ out_mem)
{
    const int bid = (int)gridDim.x - 1 - (int)blockIdx.x;
    const int b = bid >> 2;
    const int rbase = (bid & 3) * 512;
    const int tid = threadIdx.x;
    const int lane8 = tid & 7;
    const int rgrp = tid >> 3;
    const float* p = pw + (size_t)b * PSTRIDE;
    const f32x4 ea = *(const f32x4*)(p + E_OFF + lane8 * 8);
    const f32x4 eb2 = *(const f32x4*)(p + E_OFF + lane8 * 8 + 4);
    const f32x4 aa = *(const f32x4*)(p + A_OFF + lane8 * 8);
    const f32x4 ab = *(const f32x4*)(p + A_OFF + lane8 * 8 + 4);
    const float* memb = memory + (size_t)b * RR * CC;
    float* omb = out_mem + (size_t)b * RR * CC;
    const float* wb = w + (size_t)b * RR;

    #pragma unroll
    for (int mi = 0; mi < 4; ++mi) {
        f32x4 ma[4], mb[4];
        float wv[4];
        #pragma unroll
        for (int j = 0; j < 4; ++j) {
            int r = rbase + (mi * 4 + j) * 32 + rgrp;
            const f32x4* mp = (const f32x4*)(memb + (size_t)r * CC + lane8 * 8);
            ma[j] = mp[0];
            mb[j] = mp[1];
            wv[j] = wb[r];
        }
        #pragma unroll
        for (int j = 0; j < 4; ++j) {
            int r = rbase + (mi * 4 + j) * 32 + rgrp;
            f32x4 oa, ob;
            oa.x = ma[j].x * (1.f - wv[j] * ea.x) + wv[j] * aa.x;
            oa.y = ma[j].y * (1.f - wv[j] * ea.y) + wv[j] * aa.y;
            oa.z = ma[j].z * (1.f - wv[j] * ea.z) + wv[j] * aa.z;
            oa.w = ma[j].w * (1.f - wv[j] * ea.w) + wv[j] * aa.w;
            ob.x = mb[j].x * (1.f - wv[j] * eb2.x) + wv[j] * ab.x;
            ob.y = mb[j].y * (1.f - wv[j] * eb2.y) + wv[j] * ab.y;
            ob.z = mb[j].z * (1.f - wv[j] * eb2.z) + wv[j] * ab.z;
            ob.w = mb[j].w * (1.f - wv[j] * eb2.w) + wv[j] * ab.w;
            f32x4* op = (f32x4*)(omb + (size_t)r * CC + lane8 * 8);
            op[0] = oa;
            op[1] = ob;
        }
    }
}

extern "C" void kernel_launch(void* const* d_in, const int* in_sizes, int n_in,
                              void* d_out, int out_size, void* d_ws, size_t ws_size,
                              hipStream_t stream) {
    const float* h      = (const float*)d_in[0];
    const float* prev_w = (const float*)d_in[1];
    const float* memory = (const float*)d_in[2];
    const float* fc_w   = (const float*)d_in[3];
    const float* fc_b   = (const float*)d_in[4];

    float* pw      = (float*)d_ws;              // 512*208 floats
    float* out_w   = (float*)d_out;             // B*R
    float* out_mem = out_w + (size_t)BB * RR;   // B*R*C

    const size_t pw_f   = (size_t)BB * PSTRIDE;
    const size_t br_f   = (size_t)BB * RR;
    const size_t es_f   = (size_t)BB * 4;
    const size_t part_f = (size_t)BB * 4 * PART_STRIDE;
    const size_t need_f = pw_f + 2 * br_f + 2 * es_f + part_f;

    float* sc   = pw + pw_f;
    float* wp   = sc + br_f;
    float* esum = wp + br_f;
    float* psum = esum + es_f;
    float* part = psum + es_f;

    params_part_kernel<<<256, 256, 0, stream>>>(h, fc_w, part);
    params_combine_kernel<<<BB, 256, 0, stream>>>(part, fc_b, pw);

    // coop support check (device attribute query is graph-capture-safe)
    int coop_attr = 0;
    int dev = 0;
    hipGetDevice(&dev);
    hipDeviceGetAttribute(&coop_attr, hipDeviceAttributeCooperativeLaunch, dev);

    bool coop_ok = coop_attr && (ws_size >= need_f * sizeof(float));
    if (coop_ok) {
        void* args[] = {
            (void*)&memory, (void*)&prev_w, (void*)&pw, (void*)&sc,
            (void*)&esum, (void*)&wp, (void*)&psum, (void*)&out_w,
            (void*)&out_mem
        };
        hipError_t e = hipLaunchCooperativeKernel(
            (const void*)coop_kernel, dim3(BB * 2), dim3(256), args, 0, stream);
        if (e != hipSuccess) coop_ok = false;
    }

    if (!coop_ok) {
        // proven R12 path
        score_kernel<<<BB * 4, 256, 0, stream>>>(memory, pw, sc, esum);
        weight_kernel<<<BB, 256, 0, stream>>>(sc, esum, prev_w, pw, out_w);
        update_kernel<<<BB * 4, 256, 0, stream>>>(memory, out_w, pw, out_mem);
    }
}

// Round 15
// 189.575 us; speedup vs baseline: 2.1963x; 2.1963x over previous
//
#include <hip/hip_runtime.h>
#include <math.h>

// Problem constants (from reference setup_inputs)
#define BB 512
#define HH 512
#define RR 2048
#define CC 64
#define OUTD 202          // 3*64 + 2*3 + 4
// params workspace layout per batch (floats)
#define PSTRIDE 208
#define K_OFF 0
#define E_OFF 64
#define A_OFF 128
#define S_OFF 192         // 7 softmaxed shift weights
#define COMBO_OFF 199     // beta / k_n
#define G_OFF 200
#define GAMMA_OFF 201

#define PART_STRIDE 224   // padded 202, per (batch, hq) partial row

typedef float f32x4 __attribute__((ext_vector_type(4)));

__device__ __forceinline__ float softplusf_(float x) {
    return (x > 20.f) ? x : log1pf(expf(x));
}
__device__ __forceinline__ float sigmoidf_(float x) {
    return 1.f / (1.f + expf(-x));
}

// ---------------------------------------------------------------------------
// Kernel A1: split-K partial GEMM (proven R11). 256 blocks = 64 bg x 4 hq.
// ---------------------------------------------------------------------------
__global__ __launch_bounds__(256) void params_part_kernel(
    const float* __restrict__ h, const float* __restrict__ fc_w,
    float* __restrict__ part)
{
    __shared__ float h_sh[8][128];
    const int tid = threadIdx.x;
    const int bg = blockIdx.x >> 2;
    const int hq = blockIdx.x & 3;
    const int b0 = bg * 8;
    const int h0 = hq * 128;

    for (int idx = tid; idx < 8 * 128; idx += 256) {
        int j = idx >> 7, i = idx & 127;
        h_sh[j][i] = h[(size_t)(b0 + j) * HH + h0 + i];
    }
    __syncthreads();

    if (tid < OUTD) {
        float acc[8];
        #pragma unroll
        for (int j = 0; j < 8; ++j) acc[j] = 0.f;
        const float4* wr = (const float4*)(fc_w + (size_t)tid * HH + h0);
        #pragma unroll 4
        for (int i4 = 0; i4 < 32; ++i4) {
            float4 wv = wr[i4];
            int i = i4 * 4;
            #pragma unroll
            for (int j = 0; j < 8; ++j) {
                acc[j] = fmaf(wv.x, h_sh[j][i + 0], acc[j]);
                acc[j] = fmaf(wv.y, h_sh[j][i + 1], acc[j]);
                acc[j] = fmaf(wv.z, h_sh[j][i + 2], acc[j]);
                acc[j] = fmaf(wv.w, h_sh[j][i + 3], acc[j]);
            }
        }
        #pragma unroll
        for (int j = 0; j < 8; ++j) {
            part[((size_t)(b0 + j) * 4 + hq) * PART_STRIDE + tid] = acc[j];
        }
    }
}

// ---------------------------------------------------------------------------
// Kernel A2: combine partials + bias -> activations -> packed params (R11).
// ---------------------------------------------------------------------------
__global__ __launch_bounds__(256) void params_combine_kernel(
    const float* __restrict__ part, const float* __restrict__ fc_b,
    float* __restrict__ pw)
{
    __shared__ float z_sh[80];
    const int b = blockIdx.x;
    const int tid = threadIdx.x;
    float* p = pw + (size_t)b * PSTRIDE;

    if (tid < OUTD) {
        const float* q = part + (size_t)b * 4 * PART_STRIDE + tid;
        float z = q[0] + q[PART_STRIDE] + q[2 * PART_STRIDE]
                + q[3 * PART_STRIDE] + fc_b[tid];
        if (tid < 74) z_sh[tid] = z;
        if (tid < 64)                      p[K_OFF + tid] = tanhf(z);
        else if (tid == 65)                p[G_OFF] = sigmoidf_(z);
        else if (tid == 73)                p[GAMMA_OFF] = softplusf_(z) + 1.f;
        else if (tid >= 74 && tid < 138)   p[E_OFF + (tid - 74)] = sigmoidf_(z);
        else if (tid >= 138)               p[A_OFF + (tid - 138)] = tanhf(z);
    }
    __syncthreads();

    if (tid < 64) {
        float kv = tanhf(z_sh[tid]);
        float ss = kv * kv;
        #pragma unroll
        for (int m = 1; m < 64; m <<= 1) ss += __shfl_xor(ss, m, 64);
        if (tid == 0) {
            float kn = fmaxf(sqrtf(ss), 1e-8f);
            float beta = softplusf_(z_sh[64]);
            p[COMBO_OFF] = beta / kn;
            float mx = -1e30f;
            #pragma unroll
            for (int q = 0; q < 7; ++q) mx = fmaxf(mx, z_sh[66 + q]);
            float ev[7], se = 0.f;
            #pragma unroll
            for (int q = 0; q < 7; ++q) {
                ev[q] = __expf(z_sh[66 + q] - mx);
                se += ev[q];
            }
            float inv = 1.f / se;
            #pragma unroll
            for (int q = 0; q < 7; ++q) p[S_OFF + q] = ev[q] * inv;
        }
    }
}

// ---------------------------------------------------------------------------
// 256-thread block reduce, fixed order -> deterministic
// ---------------------------------------------------------------------------
__device__ __forceinline__ float block_reduce_sum4(float v, float* red) {
    #pragma unroll
    for (int m = 1; m < 64; m <<= 1) v += __shfl_xor(v, m, 64);
    int wid = threadIdx.x >> 6;
    if ((threadIdx.x & 63) == 0) red[wid] = v;
    __syncthreads();
    float x = red[0] + red[1] + red[2] + red[3];
    __syncthreads();
    return x;
}

// ---------------------------------------------------------------------------
// Kernel S: pure read streamer, 2048 x 256, 16 lanes/row.
// CHANGE vs R12: 8-row batched loads — 8 independent dwordx4 issued before
// any use (128 B/thread in flight; R7->R8 fused A/B showed this is worth
// ~20% on a streaming phase). exp fused, per-(b,quarter) exp-sums -> esum.
// Max-free softmax is exact (|arg| <= beta, small).
// ---------------------------------------------------------------------------
__global__ __launch_bounds__(256) void score_kernel(
    const float* __restrict__ memory, const float* __restrict__ pw,
    float* __restrict__ sc, float* __restrict__ esum)
{
    __shared__ float red[4];
    const int tid = threadIdx.x;
    const int b = blockIdx.x >> 2;
    const int rbase = (blockIdx.x & 3) * 512;
    const int lane16 = tid & 15;
    const int rgrp = tid >> 4;            // 0..15
    const float* p = pw + (size_t)b * PSTRIDE;
    const float4 k4 = *(const float4*)(p + K_OFF + lane16 * 4);
    const float combo = p[COMBO_OFF];
    const float* memb = memory + (size_t)b * RR * CC;

    float lsum = 0.f;
    #pragma unroll
    for (int mi = 0; mi < 4; ++mi) {
        float4 m4[8];
        #pragma unroll
        for (int j = 0; j < 8; ++j) {
            int r = rbase + (mi * 8 + j) * 16 + rgrp;
            m4[j] = *(const float4*)(memb + (size_t)r * CC + lane16 * 4);
        }
        #pragma unroll
        for (int j = 0; j < 8; ++j) {
            int r = rbase + (mi * 8 + j) * 16 + rgrp;
            float num = m4[j].x * k4.x + m4[j].y * k4.y + m4[j].z * k4.z
                      + m4[j].w * k4.w;
            float ssq = m4[j].x * m4[j].x + m4[j].y * m4[j].y
                      + m4[j].z * m4[j].z + m4[j].w * m4[j].w;
            #pragma unroll
            for (int m = 1; m < 16; m <<= 1) {
                num += __shfl_xor(num, m, 64);
                ssq += __shfl_xor(ssq, m, 64);
            }
            if (lane16 == 0) {
                float mn = fmaxf(sqrtf(ssq), 1e-8f);
                float ev = __expf(combo * num / mn);
                sc[(size_t)b * RR + r] = ev;
                lsum += ev;
            }
        }
    }
    float bs = block_reduce_sum4(lsum, red);
    if (tid == 0) esum[blockIdx.x] = bs;
}

// ---------------------------------------------------------------------------
// Kernel W: per-batch weight pipeline (proven R12, 512 x 256).
// ---------------------------------------------------------------------------
__global__ __launch_bounds__(256) void weight_kernel(
    const float* __restrict__ sc, const float* __restrict__ esum,
    const float* __restrict__ prev_w, const float* __restrict__ pw,
    float* __restrict__ out_w)
{
    __shared__ float buf[RR];
    __shared__ float wg[RR];
    __shared__ float red[4];
    const int b = blockIdx.x;
    const int tid = threadIdx.x;
    const float* p = pw + (size_t)b * PSTRIDE;
    const float g = p[G_OFF];
    const float gamma = p[GAMMA_OFF];
    const float s0 = p[S_OFF + 0], s1 = p[S_OFF + 1], s2 = p[S_OFF + 2],
                s3 = p[S_OFF + 3], s4 = p[S_OFF + 4], s5 = p[S_OFF + 5],
                s6 = p[S_OFF + 6];
    const float* eb = esum + (size_t)b * 4;
    const float se = eb[0] + eb[1] + eb[2] + eb[3];
    const float gi = g / se, omg = 1.f - g;

    #pragma unroll
    for (int t = 0; t < 4; ++t) {
        int r2 = (t * 256 + tid) * 2;
        float2 ev = *(const float2*)(sc + (size_t)b * RR + r2);
        float2 pv = *(const float2*)(prev_w + (size_t)b * RR + r2);
        wg[r2]     = gi * ev.x + omg * pv.x;
        wg[r2 + 1] = gi * ev.y + omg * pv.y;
    }
    __syncthreads();

    float lp = 0.f;
    #pragma unroll
    for (int t = 0; t < 8; ++t) {
        int r = t * 256 + tid;
        float acc = s0 * wg[(r - 3) & (RR - 1)]
                  + s1 * wg[(r - 2) & (RR - 1)]
                  + s2 * wg[(r - 1) & (RR - 1)]
                  + s3 * wg[r]
                  + s4 * wg[(r + 1) & (RR - 1)]
                  + s5 * wg[(r + 2) & (RR - 1)]
                  + s6 * wg[(r + 3) & (RR - 1)];
        float v = __powf(acc, gamma);
        buf[r] = v;
        lp += v;
    }
    const float ps = block_reduce_sum4(lp, red);   // barrier: conv reads done
    const float invp = 1.f / (ps + 1e-16f);

    #pragma unroll
    for (int t = 0; t < 4; ++t) {
        int r2 = (t * 256 + tid) * 2;
        *(float2*)(out_w + (size_t)b * RR + r2) =
            make_float2(buf[r2] * invp, buf[r2 + 1] * invp);
    }
}

// ---------------------------------------------------------------------------
// Kernel U: pure read+write streamer (2048 x 256, no barriers, reverse
// block order). CHANGE vs R12: 8-row batched loads (16 dwordx4 in flight,
// 256 B/thread). Plain loads (L3 hits on lines score allocated), PLAIN
// stores (NT = +50% WRITE_SIZE, proven R7 vs R8).
// ---------------------------------------------------------------------------
__global__ __launch_bounds__(256) void update_kernel(
    const float* __restrict__ memory, const float* __restrict__ w,
    const float* __restrict__ pw, float* __restrict__ out_mem)
{
    const int bid = (int)gridDim.x - 1 - (int)blockIdx.x;
    const int b = bid >> 2;
    const int rbase = (bid & 3) * 512;
    const int tid = threadIdx.x;
    const int lane8 = tid & 7;
    const int rgrp = tid >> 3;            // 0..31
    const float* p = pw + (size_t)b * PSTRIDE;
    const f32x4 ea = *(const f32x4*)(p + E_OFF + lane8 * 8);
    const f32x4 eb2 = *(const f32x4*)(p + E_OFF + lane8 * 8 + 4);
    const f32x4 aa = *(const f32x4*)(p + A_OFF + lane8 * 8);
    const f32x4 ab = *(const f32x4*)(p + A_OFF + lane8 * 8 + 4);
    const float* memb = memory + (size_t)b * RR * CC;
    float* omb = out_mem + (size_t)b * RR * CC;
    const float* wb = w + (size_t)b * RR;

    #pragma unroll
    for (int mi = 0; mi < 2; ++mi) {
        f32x4 ma[8], mb[8];
        float wv[8];
        #pragma unroll
        for (int j = 0; j < 8; ++j) {
            int r = rbase + (mi * 8 + j) * 32 + rgrp;
            const f32x4* mp = (const f32x4*)(memb + (size_t)r * CC + lane8 * 8);
            ma[j] = mp[0];
            mb[j] = mp[1];
            wv[j] = wb[r];
        }
        #pragma unroll
        for (int j = 0; j < 8; ++j) {
            int r = rbase + (mi * 8 + j) * 32 + rgrp;
            f32x4 oa, ob;
            oa.x = ma[j].x * (1.f - wv[j] * ea.x) + wv[j] * aa.x;
            oa.y = ma[j].y * (1.f - wv[j] * ea.y) + wv[j] * aa.y;
            oa.z = ma[j].z * (1.f - wv[j] * ea.z) + wv[j] * aa.z;
            oa.w = ma[j].w * (1.f - wv[j] * ea.w) + wv[j] * aa.w;
            ob.x = mb[j].x * (1.f - wv[j] * eb2.x) + wv[j] * ab.x;
            ob.y = mb[j].y * (1.f - wv[j] * eb2.y) + wv[j] * ab.y;
            ob.z = mb[j].z * (1.f - wv[j] * eb2.z) + wv[j] * ab.z;
            ob.w = mb[j].w * (1.f - wv[j] * eb2.w) + wv[j] * ab.w;
            f32x4* op = (f32x4*)(omb + (size_t)r * CC + lane8 * 8);
            op[0] = oa;
            op[1] = ob;
        }
    }
}

extern "C" void kernel_launch(void* const* d_in, const int* in_sizes, int n_in,
                              void* d_out, int out_size, void* d_ws, size_t ws_size,
                              hipStream_t stream) {
    const float* h      = (const float*)d_in[0];
    const float* prev_w = (const float*)d_in[1];
    const float* memory = (const float*)d_in[2];
    const float* fc_w   = (const float*)d_in[3];
    const float* fc_b   = (const float*)d_in[4];

    float* pw      = (float*)d_ws;              // 512*208 floats
    float* out_w   = (float*)d_out;             // B*R
    float* out_mem = out_w + (size_t)BB * RR;   // B*R*C

    const size_t pw_f   = (size_t)BB * PSTRIDE;
    const size_t br_f   = (size_t)BB * RR;
    const size_t es_f   = (size_t)BB * 4;
    const size_t part_f = (size_t)BB * 4 * PART_STRIDE;
    const size_t need_f = pw_f + br_f + es_f + part_f;

    float* sc   = pw + pw_f;
    float* esum = sc + br_f;
    float* part = esum + es_f;

    if (ws_size >= need_f * sizeof(float)) {
        params_part_kernel<<<256, 256, 0, stream>>>(h, fc_w, part);
        params_combine_kernel<<<BB, 256, 0, stream>>>(part, fc_b, pw);
        score_kernel<<<BB * 4, 256, 0, stream>>>(memory, pw, sc, esum);
        weight_kernel<<<BB, 256, 0, stream>>>(sc, esum, prev_w, pw, out_w);
        update_kernel<<<BB * 4, 256, 0, stream>>>(memory, out_w, pw, out_mem);
    } else {
        // fallback (ws ~800 MB in practice; safe path anyway): sc aliased
        // onto out_mem head — fully read before update overwrites, ordered
        // by kernel boundaries.
        float* sc_fb   = out_mem;
        float* esum_fb = pw + pw_f;
        float* part_fb = esum_fb + es_f;
        params_part_kernel<<<256, 256, 0, stream>>>(h, fc_w, part_fb);
        params_combine_kernel<<<BB, 256, 0, stream>>>(part_fb, fc_b, pw);
        score_kernel<<<BB * 4, 256, 0, stream>>>(memory, pw, sc_fb, esum_fb);
        weight_kernel<<<BB, 256, 0, stream>>>(sc_fb, esum_fb, prev_w, pw, out_w);
        update_kernel<<<BB * 4, 256, 0, stream>>>(memory, out_w, pw, out_mem);
    }
}